// Round 6
// baseline (305.353 us; speedup 1.0000x reference)
//
#include <hip/hip_runtime.h>
#include <stdint.h>
#include <math.h>

#define B_ 4
#define S_ 1024
#define E_ 1024
#define H_ 16
#define HD_ 64
#define HB_ 64  // H_*B_

typedef __attribute__((ext_vector_type(8))) short bhalf8;
typedef __attribute__((ext_vector_type(4))) float floatx4;

__device__ __forceinline__ unsigned short f2bf(float f) {
  union { float f; unsigned u; } v; v.f = f;
  unsigned r = (v.u + 0x7FFFu + ((v.u >> 16) & 1u)) >> 16;
  return (unsigned short)r;
}
__device__ __forceinline__ float bf2f(unsigned short b) {
  union { unsigned u; float f; } v; v.u = ((unsigned)b) << 16;
  return v.f;
}
// 2x f32 -> packed bf16 (RTNE), low half = a, high half = b
__device__ __forceinline__ unsigned cvtpk_bf16(float a, float b) {
  unsigned r;
  asm volatile("v_cvt_pk_bf16_f32 %0, %1, %2" : "=v"(r) : "v"(a), "v"(b));
  return r;
}

__device__ __forceinline__ void gload16(const void* g, void* l) {
  __builtin_amdgcn_global_load_lds(
      (const __attribute__((address_space(1))) unsigned int*)g,
      (__attribute__((address_space(3))) unsigned int*)l, 16, 0, 0);
}

// Stage NCH*8 rows x 64 bf16 (128B rows, global row stride 1024 elems) into
// LDS, linear dest + inverse-swizzled source (involution: byte ^= (row&7)<<4).
template <int NCH>
__device__ __forceinline__ void stage_tile(const unsigned short* org,
                                           unsigned short* lds, int wave, int lane) {
  const int rl = lane >> 3;                      // row within 8-row chunk
  const int scb = ((lane & 7) << 4) ^ (rl << 4); // pre-swizzled source col byte
  const char* base = (const char*)org + scb;
#pragma unroll
  for (int i = 0; i < NCH / 4; ++i) {
    const int c = wave + 4 * i;
    gload16(base + (size_t)(c * 8 + rl) * 2048, (char*)lds + c * 1024);
  }
}

// Read one MFMA operand fragment (8 contiguous bf16) with the matching swizzle.
__device__ __forceinline__ bhalf8 read_frag(const unsigned short* lds, int row, int kbyte) {
  const int off = row * 128 + (kbyte ^ ((row & 7) << 4));
  return *(const bhalf8*)((const char*)lds + off);
}

// ---------------------------------------------------------------------------
__global__ void detect_bool_kernel(const uint8_t* __restrict__ amask, int* __restrict__ flag) {
  if (threadIdx.x == 0 && blockIdx.x == 0) *flag = (amask[1] != 0) ? 1 : 0;
}

// fp32 -> bf16 for the 3 activation inputs (z selects tensor)
__global__ __launch_bounds__(256) void cvt_in_kernel(
    const float* __restrict__ q, const float* __restrict__ k,
    const float* __restrict__ v, unsigned short* __restrict__ Ab) {
  const int z = blockIdx.z;
  const float* src = (z == 0) ? q : (z == 1) ? k : v;
  unsigned short* dst = Ab + (size_t)z * 4194304;
  const size_t i = ((size_t)blockIdx.x * 256 + threadIdx.x) * 8;
  float4 a = *(const float4*)(src + i);
  float4 b = *(const float4*)(src + i + 4);
  bhalf8 r;
  r[0] = (short)f2bf(a.x); r[1] = (short)f2bf(a.y);
  r[2] = (short)f2bf(a.z); r[3] = (short)f2bf(a.w);
  r[4] = (short)f2bf(b.x); r[5] = (short)f2bf(b.y);
  r[6] = (short)f2bf(b.z); r[7] = (short)f2bf(b.w);
  *(bhalf8*)(dst + i) = r;
}

// fp32 -> bf16 for the 4 weight matrices
__global__ __launch_bounds__(256) void cvt_w_kernel(
    const float* __restrict__ wq, const float* __restrict__ wk,
    const float* __restrict__ wv, const float* __restrict__ wo,
    unsigned short* __restrict__ Wb) {
  const int z = blockIdx.z;
  const float* src = (z == 0) ? wq : (z == 1) ? wk : (z == 2) ? wv : wo;
  unsigned short* dst = Wb + (size_t)z * 1048576;
  const size_t i = ((size_t)blockIdx.x * 256 + threadIdx.x) * 8;
  float4 a = *(const float4*)(src + i);
  float4 b = *(const float4*)(src + i + 4);
  bhalf8 r;
  r[0] = (short)f2bf(a.x); r[1] = (short)f2bf(a.y);
  r[2] = (short)f2bf(a.z); r[3] = (short)f2bf(a.w);
  r[4] = (short)f2bf(b.x); r[5] = (short)f2bf(b.y);
  r[6] = (short)f2bf(b.z); r[7] = (short)f2bf(b.w);
  *(bhalf8*)(dst + i) = r;
}

// ---------------------------------------------------------------------------
// C[4096,1024] = A @ W^T + bias. 128x128 tile, BK=64, 4 waves (2x2 quadrants).
// XCD-chunked swizzle on the 256-block (x,y) grid for L2 locality.
// ---------------------------------------------------------------------------
template <bool BF16OUT>
__global__ __launch_bounds__(256) void mfma_gemm_kernel(
    const unsigned short* __restrict__ A0, const unsigned short* __restrict__ A1,
    const unsigned short* __restrict__ A2,
    const unsigned short* __restrict__ W0, const unsigned short* __restrict__ W1,
    const unsigned short* __restrict__ W2,
    const float* __restrict__ b0, const float* __restrict__ b1,
    const float* __restrict__ b2,
    void* __restrict__ C0, void* __restrict__ C1, void* __restrict__ C2) {
  const int z = blockIdx.z;
  const unsigned short* A = (z == 0) ? A0 : (z == 1) ? A1 : A2;
  const unsigned short* W = (z == 0) ? W0 : (z == 1) ? W1 : W2;
  const float* bias = (z == 0) ? b0 : (z == 1) ? b1 : b2;
  void* C = (z == 0) ? C0 : (z == 1) ? C1 : C2;
  const int lin = blockIdx.y * 8 + blockIdx.x;
  const int swz = (lin & 7) * 32 + (lin >> 3);
  const int m0 = (swz >> 3) * 128, n0 = (swz & 7) * 128;
  __shared__ unsigned short As[128 * 64];
  __shared__ unsigned short Ws[128 * 64];
  const int t = threadIdx.x, wave = t >> 6, lane = t & 63;
  const int wr = wave >> 1, wc = wave & 1;
  floatx4 acc[4][4];
  const floatx4 z4 = {0.f, 0.f, 0.f, 0.f};
#pragma unroll
  for (int i = 0; i < 4; ++i)
#pragma unroll
    for (int j = 0; j < 4; ++j) acc[i][j] = z4;

  for (int k0 = 0; k0 < 1024; k0 += 64) {
    stage_tile<16>(A + (size_t)m0 * 1024 + k0, As, wave, lane);
    stage_tile<16>(W + (size_t)n0 * 1024 + k0, Ws, wave, lane);
    __syncthreads();
#pragma unroll
    for (int ks = 0; ks < 2; ++ks) {
      const int kb = ks * 64 + ((lane >> 4) << 4);
      bhalf8 af[4], bf[4];
#pragma unroll
      for (int mi = 0; mi < 4; ++mi)
        af[mi] = read_frag(As, wr * 64 + mi * 16 + (lane & 15), kb);
#pragma unroll
      for (int ni = 0; ni < 4; ++ni)
        bf[ni] = read_frag(Ws, wc * 64 + ni * 16 + (lane & 15), kb);
#pragma unroll
      for (int mi = 0; mi < 4; ++mi)
#pragma unroll
        for (int ni = 0; ni < 4; ++ni)
          acc[mi][ni] = __builtin_amdgcn_mfma_f32_16x16x32_bf16(af[mi], bf[ni], acc[mi][ni], 0, 0, 0);
    }
    __syncthreads();
  }
#pragma unroll
  for (int mi = 0; mi < 4; ++mi)
#pragma unroll
    for (int ni = 0; ni < 4; ++ni) {
      const int col = n0 + wc * 64 + ni * 16 + (lane & 15);
      const float bv = bias[col];
#pragma unroll
      for (int r = 0; r < 4; ++r) {
        const int row = m0 + wr * 64 + mi * 16 + (lane >> 4) * 4 + r;
        const float v = acc[mi][ni][r] + bv;
        if (BF16OUT)
          ((unsigned short*)C)[(size_t)row * 1024 + col] = f2bf(v);
        else
          ((float*)C)[(size_t)row * 1024 + col] = v;
      }
    }
}

// ---------------------------------------------------------------------------
// In-place RoPE on bf16 [B,S,E]; one thread per channel pair.
// ---------------------------------------------------------------------------
__global__ __launch_bounds__(256) void rope_bf_kernel(unsigned int* __restrict__ X,
                                                      const int* __restrict__ idxs) {
  const int gid = blockIdx.x * 256 + threadIdx.x;
  const int i = gid & 511, bs = gid >> 9;
  const int pos = idxs[bs];
  const double freq = exp(-(double)(2 * i) * (9.210340371976184 / 1024.0));
  const double ang = fmod((double)pos * freq, 6.283185307179586476925287);
  const float fa = (float)ang;
  float sn, c;
  sincosf(fa, &sn, &c);
  const unsigned v = X[gid];
  const float x = bf2f((unsigned short)(v & 0xffffu));
  const float y = bf2f((unsigned short)(v >> 16));
  const float rx = x * c - y * sn;
  const float ry = x * sn + y * c;
  X[gid] = (unsigned)f2bf(rx) | ((unsigned)f2bf(ry) << 16);
}

// ---------------------------------------------------------------------------
// Vt[(b*16+h)*64 + d][s] = Vr[b][s][h*64+d]   (bf16 transpose, 64x64 tiles)
// ---------------------------------------------------------------------------
__global__ __launch_bounds__(256) void transpose_v_kernel(
    const unsigned short* __restrict__ Vr, unsigned short* __restrict__ Vt) {
  const int s0 = blockIdx.x * 64;
  const int bh = blockIdx.y;
  const int b = bh >> 4, h = bh & 15;
  __shared__ unsigned short L[64][72];
  const int t = threadIdx.x, r = t >> 2, cq = (t & 3) * 16;
  const unsigned short* src = Vr + ((size_t)(b * S_) + s0 + r) * E_ + h * HD_ + cq;
  *(bhalf8*)&L[r][cq] = *(const bhalf8*)src;
  *(bhalf8*)&L[r][cq + 8] = *(const bhalf8*)(src + 8);
  __syncthreads();
  bhalf8 o0, o1;
#pragma unroll
  for (int u = 0; u < 8; ++u) o0[u] = (short)L[cq + u][r];
#pragma unroll
  for (int u = 0; u < 8; ++u) o1[u] = (short)L[cq + 8 + u][r];
  unsigned short* dst = Vt + ((size_t)bh * 64 + r) * 1024 + s0 + cq;
  *(bhalf8*)dst = o0;
  *(bhalf8*)(dst + 8) = o1;
}

// ---------------------------------------------------------------------------
// scores + in-register softmax + P write + PV, one head-batch per block.
// grid (64 qb, CH). 4 waves, 33KB LDS.
//  QK^T swapped operands: lane (w,l4,l15) holds S[q=l15][k=w*256+mt*16+l4*4+r]
//  in 64 regs. Mask/max/exp/sum fully in-reg (tree + 2 shfl + 64-float LDS).
//  P packed via v_cvt_pk_bf16_f32 into swizzled LDS, copied out coalesced for
//  wmean, and consumed in-LDS as the PV MFMA A-operand (wave w owns d-tile w).
// ---------------------------------------------------------------------------
__global__ __launch_bounds__(256) void scores_pv_kernel(
    const unsigned short* __restrict__ Qr, const unsigned short* __restrict__ Kr,
    const unsigned short* __restrict__ Vt, unsigned short* __restrict__ Ocat,
    unsigned short* __restrict__ P, const void* __restrict__ amask,
    const void* __restrict__ kpm, const int* __restrict__ flagp, int hb0) {
  const int lhb = blockIdx.y, hb = hb0 + lhb;
  const int h = hb >> 2, b = hb & 3, bp = hb >> 4;
  const int q0 = blockIdx.x * 16;
  __shared__ unsigned short Sbuf[16 * 1024];  // bf16 P, XOR-swizzled rows
  __shared__ float rmax[64];
  __shared__ float rsum[64];
  const int t = threadIdx.x, w = t >> 6, lane = t & 63;
  const int l4 = lane >> 4, l15 = lane & 15;
  const int isu8 = *flagp;

  const char* Qb = (const char*)Qr + ((size_t)b << 21) + h * 128;
  const char* Kb = (const char*)Kr + ((size_t)b << 21) + h * 128;

  // Q fragments (B-operand; rows q0+l15)
  bhalf8 bq0 = *(const bhalf8*)(Qb + (size_t)(q0 + l15) * 2048 + l4 * 16);
  bhalf8 bq1 = *(const bhalf8*)(Qb + (size_t)(q0 + l15) * 2048 + 64 + l4 * 16);

  // QK^T: wave w covers k in [w*256, w*256+256)
  floatx4 acc[16];
  const floatx4 z4 = {0.f, 0.f, 0.f, 0.f};
#pragma unroll
  for (int i = 0; i < 16; ++i) acc[i] = z4;
#pragma unroll
  for (int mt = 0; mt < 16; ++mt) {
    const char* kr = Kb + (size_t)(w * 256 + mt * 16 + l15) * 2048 + l4 * 16;
    bhalf8 a0 = *(const bhalf8*)kr;
    bhalf8 a1 = *(const bhalf8*)(kr + 64);
    acc[mt] = __builtin_amdgcn_mfma_f32_16x16x32_bf16(a0, bq0, acc[mt], 0, 0, 0);
    acc[mt] = __builtin_amdgcn_mfma_f32_16x16x32_bf16(a1, bq1, acc[mt], 0, 0, 0);
  }

  // Build per-lane mask bits for (q=l15, k=w*256+mt*16+l4*4+{0..3}).
  unsigned mb0 = 0, mb1 = 0;
  if (isu8) {
    const uint8_t* ap = (const uint8_t*)amask + (size_t)(q0 + l15) * 1024;
    const uint8_t* kp = (const uint8_t*)kpm + (size_t)bp * 1024;
#pragma unroll
    for (int mt = 0; mt < 16; ++mt) {
      const int k = w * 256 + mt * 16 + l4 * 4;
      uchar4 a = *(const uchar4*)(ap + k);
      uchar4 c = *(const uchar4*)(kp + k);
      unsigned bits = ((a.x | c.x) ? 1u : 0u) | ((a.y | c.y) ? 2u : 0u) |
                      ((a.z | c.z) ? 4u : 0u) | ((a.w | c.w) ? 8u : 0u);
      if (mt < 8) mb0 |= bits << (mt * 4);
      else        mb1 |= bits << ((mt - 8) * 4);
    }
  } else {
    const int* ap = (const int*)amask + (size_t)(q0 + l15) * 1024;
    const int* kp = (const int*)kpm + (size_t)bp * 1024;
#pragma unroll
    for (int mt = 0; mt < 16; ++mt) {
      const int k = w * 256 + mt * 16 + l4 * 4;
      int4 a = *(const int4*)(ap + k);
      int4 c = *(const int4*)(kp + k);
      unsigned bits = ((a.x | c.x) ? 1u : 0u) | ((a.y | c.y) ? 2u : 0u) |
                      ((a.z | c.z) ? 4u : 0u) | ((a.w | c.w) ? 8u : 0u);
      if (mt < 8) mb0 |= bits << (mt * 4);
      else        mb1 |= bits << ((mt - 8) * 4);
    }
  }
#pragma unroll
  for (int mt = 0; mt < 16; ++mt) {
    const unsigned bits = ((mt < 8) ? (mb0 >> (mt * 4)) : (mb1 >> ((mt - 8) * 4))) & 0xFu;
#pragma unroll
    for (int r = 0; r < 4; ++r)
      if ((bits >> r) & 1u) acc[mt][r] = -INFINITY;
  }

  // Row max: in-reg tree -> 2 shfl (l4 group) -> cross-wave via LDS.
  float red[16];
#pragma unroll
  for (int mt = 0; mt < 16; ++mt)
    red[mt] = fmaxf(fmaxf(acc[mt][0], acc[mt][1]), fmaxf(acc[mt][2], acc[mt][3]));
#pragma unroll
  for (int s2 = 8; s2 > 0; s2 >>= 1)
#pragma unroll
    for (int i = 0; i < 8; ++i)
      if (i < s2) red[i] = fmaxf(red[i], red[i + s2]);
  float mx = red[0];
  mx = fmaxf(mx, __shfl_xor(mx, 16));
  mx = fmaxf(mx, __shfl_xor(mx, 32));
  if (l4 == 0) rmax[w * 16 + l15] = mx;
  __syncthreads();
  mx = fmaxf(fmaxf(rmax[l15], rmax[16 + l15]), fmaxf(rmax[32 + l15], rmax[48 + l15]));

  // exp2 with folded 1/8 scale; masked entries are -inf -> 0.
  const float Cc = 0.18033688011112042f;  // 0.125 * log2(e)
  const float mc = mx * Cc;
#pragma unroll
  for (int mt = 0; mt < 16; ++mt)
#pragma unroll
    for (int r = 0; r < 4; ++r)
      acc[mt][r] = exp2f(__builtin_fmaf(acc[mt][r], Cc, -mc));

  // Row sum: same reduction shape.
#pragma unroll
  for (int mt = 0; mt < 16; ++mt)
    red[mt] = (acc[mt][0] + acc[mt][1]) + (acc[mt][2] + acc[mt][3]);
#pragma unroll
  for (int s2 = 8; s2 > 0; s2 >>= 1)
#pragma unroll
    for (int i = 0; i < 8; ++i)
      if (i < s2) red[i] += red[i + s2];
  float sm = red[0];
  sm += __shfl_xor(sm, 16);
  sm += __shfl_xor(sm, 32);
  if (l4 == 0) rsum[w * 16 + l15] = sm;
  __syncthreads();
  sm = (rsum[l15] + rsum[16 + l15]) + (rsum[32 + l15] + rsum[48 + l15]);
  const float inv = 1.0f / sm;

  // Normalize, pack to bf16, write into swizzled Sbuf.
  const int xr = (l15 & 7) << 4;
#pragma unroll
  for (int mt = 0; mt < 16; ++mt) {
    uint2 pk;
    pk.x = cvtpk_bf16(acc[mt][0] * inv, acc[mt][1] * inv);
    pk.y = cvtpk_bf16(acc[mt][2] * inv, acc[mt][3] * inv);
    const int kb2 = (w * 256 + mt * 16 + l4 * 4) * 2;
    *(uint2*)((char*)Sbuf + l15 * 2048 + (kb2 ^ xr)) = pk;
  }
  __syncthreads();

  // Coalesced P copy-out (for wmean): wave w handles rows w*4..w*4+3.
  unsigned short* pbase = P + ((size_t)lhb << 20);
#pragma unroll
  for (int rr = 0; rr < 4; ++rr) {
    const int ql = w * 4 + rr;
    const int gq = q0 + ql;
    const int xq = (ql & 7) << 4;
#pragma unroll
    for (int j = 0; j < 2; ++j) {
      bhalf8 v = *(const bhalf8*)((const char*)Sbuf + ql * 2048 +
                                  ((j * 1024 + lane * 16) ^ xq));
      *(bhalf8*)(pbase + ((size_t)gq << 10) + j * 512 + lane * 8) = v;
    }
  }

  // PV: wave w owns d-tile [w*16, w*16+16), full k=1024 (2 acc chains).
  const char* Vb = (const char*)Vt +
      ((size_t)((b * 16 + h) * 64 + w * 16 + l15)) * 2048;
  floatx4 oa = z4, ob = z4;
#pragma unroll
  for (int ks = 0; ks < 16; ++ks) {
    bhalf8 pa = *(const bhalf8*)((const char*)Sbuf + l15 * 2048 +
                                 ((ks * 64 + l4 * 16) ^ xr));
    bhalf8 vb = *(const bhalf8*)(Vb + ks * 64 + l4 * 16);
    oa = __builtin_amdgcn_mfma_f32_16x16x32_bf16(pa, vb, oa, 0, 0, 0);
  }
#pragma unroll
  for (int ks = 16; ks < 32; ++ks) {
    bhalf8 pa = *(const bhalf8*)((const char*)Sbuf + l15 * 2048 +
                                 ((ks * 64 + l4 * 16) ^ xr));
    bhalf8 vb = *(const bhalf8*)(Vb + ks * 64 + l4 * 16);
    ob = __builtin_amdgcn_mfma_f32_16x16x32_bf16(pa, vb, ob, 0, 0, 0);
  }
#pragma unroll
  for (int r = 0; r < 4; ++r) {
    const int q = q0 + l4 * 4 + r;
    Ocat[((size_t)(b * 1024) + q) * 1024 + h * 64 + w * 16 + l15] =
        f2bf(oa[r] + ob[r]);
  }
}

// ---------------------------------------------------------------------------
// outW[b][q][k] += (1/16) * sum_hh P[hh*4+b][q][k]   (this chunk's heads)
// ---------------------------------------------------------------------------
__global__ __launch_bounds__(256) void wmean_kernel(
    const unsigned short* __restrict__ P, float* __restrict__ outW,
    int nhh, int first) {
  const size_t gid = (size_t)blockIdx.x * 256 + threadIdx.x;  // one per 8 k
  const int k8 = (int)(gid & 127);
  const int q = (int)((gid >> 7) & 1023);
  const int b = (int)(gid >> 17);
  float s[8];
#pragma unroll
  for (int u = 0; u < 8; ++u) s[u] = 0.f;
  for (int hh = 0; hh < nhh; ++hh) {
    const int lhb = hh * 4 + b;
    bhalf8 v = *(const bhalf8*)(P + ((size_t)lhb << 20) + ((size_t)q << 10) + k8 * 8);
#pragma unroll
    for (int u = 0; u < 8; ++u) s[u] += bf2f((unsigned short)v[u]);
  }
  float* o = outW + (((size_t)(b * S_ + q)) << 10) + k8 * 8;
  const float invH = 1.0f / 16.0f;
  float4 v0, v1;
  v0.x = s[0] * invH; v0.y = s[1] * invH; v0.z = s[2] * invH; v0.w = s[3] * invH;
  v1.x = s[4] * invH; v1.y = s[5] * invH; v1.z = s[6] * invH; v1.w = s[7] * invH;
  if (!first) {
    float4 a = *(float4*)o, b4 = *(float4*)(o + 4);
    v0.x += a.x; v0.y += a.y; v0.z += a.z; v0.w += a.w;
    v1.x += b4.x; v1.y += b4.y; v1.z += b4.z; v1.w += b4.w;
  }
  *(float4*)o = v0;
  *(float4*)(o + 4) = v1;
}

// ---------------------------------------------------------------------------
extern "C" void kernel_launch(void* const* d_in, const int* in_sizes, int n_in,
                              void* d_out, int out_size, void* d_ws, size_t ws_size,
                              hipStream_t stream) {
  (void)in_sizes; (void)n_in; (void)out_size;
  const float* query = (const float*)d_in[0];
  const float* key   = (const float*)d_in[1];
  const float* value = (const float*)d_in[2];
  const int* qidx = (const int*)d_in[3];
  const int* kidx = (const int*)d_in[4];
  const void* amask = d_in[5];
  const void* kpm   = d_in[6];
  const float* Wq = (const float*)d_in[7];
  const float* bq = (const float*)d_in[8];
  const float* Wk = (const float*)d_in[9];
  const float* bk = (const float*)d_in[10];
  const float* Wv = (const float*)d_in[11];
  const float* bv = (const float*)d_in[12];
  const float* Wo = (const float*)d_in[13];
  const float* bo = (const float*)d_in[14];

  float* outA = (float*)d_out;                          // [B,S,E] fp32
  float* outW = (float*)d_out + (size_t)B_ * S_ * E_;   // [B,S,S] fp32

  float* ws = (float*)d_ws;
  unsigned short* Ab   = (unsigned short*)(ws + 0);         // 3x 4,194,304 bf16
  unsigned short* Wb   = (unsigned short*)(ws + 6291456);   // 4x 1,048,576 bf16
  unsigned short* Qr   = (unsigned short*)(ws + 8388608);
  unsigned short* Kr   = (unsigned short*)(ws + 10485760);
  unsigned short* Vr   = (unsigned short*)(ws + 12582912);
  unsigned short* Vt   = (unsigned short*)(ws + 14680064);
  unsigned short* Ocat = (unsigned short*)(ws + 16777216);
  int* flagp           = (int*)(ws + 18874368);
  const size_t tail_off = 18874432;  // floats

  // P chunk: per head-batch 1024*1024 bf16 = 524288 floats.
  const size_t ws_floats = ws_size / 4;
  int CH = 0;
  unsigned short* P = nullptr;
  for (int c = 64; c >= 4; c >>= 1) {
    if (tail_off + (size_t)c * 524288 <= ws_floats) {
      CH = c;
      P = (unsigned short*)(ws + tail_off);
      break;
    }
  }
  if (!CH) {  // alias the Ab region (dead after the QKV GEMM): 6.29M floats >= 8 planes
    CH = 8;
    P = (unsigned short*)ws;
  }

  detect_bool_kernel<<<1, 64, 0, stream>>>((const uint8_t*)amask, flagp);

  cvt_in_kernel<<<dim3(2048, 1, 3), 256, 0, stream>>>(query, key, value, Ab);
  cvt_w_kernel<<<dim3(512, 1, 4), 256, 0, stream>>>(Wq, Wk, Wv, Wo, Wb);

  mfma_gemm_kernel<true><<<dim3(8, 32, 3), 256, 0, stream>>>(
      Ab, Ab + 4194304, Ab + 8388608,
      Wb, Wb + 1048576, Wb + 2097152,
      bq, bk, bv, Qr, Kr, Vr);

  rope_bf_kernel<<<8192, 256, 0, stream>>>((unsigned int*)Qr, qidx);
  rope_bf_kernel<<<8192, 256, 0, stream>>>((unsigned int*)Kr, kidx);

  transpose_v_kernel<<<dim3(16, 64), 256, 0, stream>>>(Vr, Vt);

  const int nch = HB_ / CH;
  for (int c = 0; c < nch; ++c) {
    const int hb0 = c * CH;
    scores_pv_kernel<<<dim3(64, CH), 256, 0, stream>>>(Qr, Kr, Vt, Ocat, P,
                                                       amask, kpm, flagp, hb0);
    wmean_kernel<<<2048, 256, 0, stream>>>(P, outW, CH / 4, (c == 0) ? 1 : 0);
  }

  mfma_gemm_kernel<false><<<dim3(8, 32, 1), 256, 0, stream>>>(
      Ocat, Ocat, Ocat, Wb + 3145728, Wb + 3145728, Wb + 3145728,
      bo, bo, bo, outA, outA, outA);
}

// Round 7
// 241.343 us; speedup vs baseline: 1.2652x; 1.2652x over previous
//
#include <hip/hip_runtime.h>
#include <stdint.h>
#include <math.h>

#define B_ 4
#define S_ 1024
#define E_ 1024
#define H_ 16
#define HD_ 64
#define HB_ 64  // H_*B_

typedef __attribute__((ext_vector_type(8))) short bhalf8;
typedef __attribute__((ext_vector_type(4))) float floatx4;

__device__ __forceinline__ unsigned short f2bf(float f) {
  union { float f; unsigned u; } v; v.f = f;
  unsigned r = (v.u + 0x7FFFu + ((v.u >> 16) & 1u)) >> 16;
  return (unsigned short)r;
}
__device__ __forceinline__ float bf2f(unsigned short b) {
  union { unsigned u; float f; } v; v.u = ((unsigned)b) << 16;
  return v.f;
}
// 2x f32 -> packed bf16 (RTNE), low half = a, high half = b
__device__ __forceinline__ unsigned cvtpk_bf16(float a, float b) {
  unsigned r;
  asm volatile("v_cvt_pk_bf16_f32 %0, %1, %2" : "=v"(r) : "v"(a), "v"(b));
  return r;
}

__device__ __forceinline__ void gload16(const void* g, void* l) {
  __builtin_amdgcn_global_load_lds(
      (const __attribute__((address_space(1))) unsigned int*)g,
      (__attribute__((address_space(3))) unsigned int*)l, 16, 0, 0);
}

// Stage NCH*8 rows x 64 bf16 (128B rows, global row stride 1024 elems) into
// LDS, linear dest + inverse-swizzled source (involution: byte ^= (row&7)<<4).
template <int NCH>
__device__ __forceinline__ void stage_tile(const unsigned short* org,
                                           unsigned short* lds, int wave, int lane) {
  const int rl = lane >> 3;                      // row within 8-row chunk
  const int scb = ((lane & 7) << 4) ^ (rl << 4); // pre-swizzled source col byte
  const char* base = (const char*)org + scb;
#pragma unroll
  for (int i = 0; i < NCH / 4; ++i) {
    const int c = wave + 4 * i;
    gload16(base + (size_t)(c * 8 + rl) * 2048, (char*)lds + c * 1024);
  }
}

// Read one MFMA operand fragment (8 contiguous bf16) with the matching swizzle.
__device__ __forceinline__ bhalf8 read_frag(const unsigned short* lds, int row, int kbyte) {
  const int off = row * 128 + (kbyte ^ ((row & 7) << 4));
  return *(const bhalf8*)((const char*)lds + off);
}

// ---------------------------------------------------------------------------
__global__ void detect_bool_kernel(const uint8_t* __restrict__ amask, int* __restrict__ flag) {
  if (threadIdx.x == 0 && blockIdx.x == 0) *flag = (amask[1] != 0) ? 1 : 0;
}

// Combined mask bits: Mbits[bp][q][word] bit j = amask[q][word*64+j] || kpm[bp][...]
__global__ __launch_bounds__(256) void mprep_kernel(
    const void* __restrict__ amask, const void* __restrict__ kpm,
    const int* __restrict__ flagp, unsigned long long* __restrict__ Mbits) {
  const int gid = blockIdx.x * 256 + threadIdx.x;  // 65536
  const int word = gid & 15, q = (gid >> 4) & 1023, bp = gid >> 14;
  const int k0 = word * 64;
  unsigned long long bits = 0;
  if (*flagp) {
    const uint8_t* ap = (const uint8_t*)amask + (size_t)q * 1024 + k0;
    const uint8_t* kp = (const uint8_t*)kpm + (size_t)bp * 1024 + k0;
#pragma unroll
    for (int c = 0; c < 4; ++c) {
      uint4 a = *(const uint4*)(ap + c * 16);
      uint4 k = *(const uint4*)(kp + c * 16);
      unsigned aw[4] = {a.x | k.x, a.y | k.y, a.z | k.z, a.w | k.w};
#pragma unroll
      for (int wv = 0; wv < 4; ++wv)
#pragma unroll
        for (int bt = 0; bt < 4; ++bt)
          if ((aw[wv] >> (8 * bt)) & 0xffu)
            bits |= 1ull << (c * 16 + wv * 4 + bt);
    }
  } else {
    const int* ap = (const int*)amask + (size_t)q * 1024 + k0;
    const int* kp = (const int*)kpm + (size_t)bp * 1024 + k0;
#pragma unroll
    for (int c = 0; c < 16; ++c) {
      int4 a = *(const int4*)(ap + c * 4);
      int4 k = *(const int4*)(kp + c * 4);
      if (a.x | k.x) bits |= 1ull << (c * 4 + 0);
      if (a.y | k.y) bits |= 1ull << (c * 4 + 1);
      if (a.z | k.z) bits |= 1ull << (c * 4 + 2);
      if (a.w | k.w) bits |= 1ull << (c * 4 + 3);
    }
  }
  Mbits[((size_t)bp << 14) + (size_t)q * 16 + word] = bits;
}

// fp32 -> bf16 for the 3 activation inputs (z selects tensor)
__global__ __launch_bounds__(256) void cvt_in_kernel(
    const float* __restrict__ q, const float* __restrict__ k,
    const float* __restrict__ v, unsigned short* __restrict__ Ab) {
  const int z = blockIdx.z;
  const float* src = (z == 0) ? q : (z == 1) ? k : v;
  unsigned short* dst = Ab + (size_t)z * 4194304;
  const size_t i = ((size_t)blockIdx.x * 256 + threadIdx.x) * 8;
  float4 a = *(const float4*)(src + i);
  float4 b = *(const float4*)(src + i + 4);
  bhalf8 r;
  r[0] = (short)f2bf(a.x); r[1] = (short)f2bf(a.y);
  r[2] = (short)f2bf(a.z); r[3] = (short)f2bf(a.w);
  r[4] = (short)f2bf(b.x); r[5] = (short)f2bf(b.y);
  r[6] = (short)f2bf(b.z); r[7] = (short)f2bf(b.w);
  *(bhalf8*)(dst + i) = r;
}

// fp32 -> bf16 for the 4 weight matrices
__global__ __launch_bounds__(256) void cvt_w_kernel(
    const float* __restrict__ wq, const float* __restrict__ wk,
    const float* __restrict__ wv, const float* __restrict__ wo,
    unsigned short* __restrict__ Wb) {
  const int z = blockIdx.z;
  const float* src = (z == 0) ? wq : (z == 1) ? wk : (z == 2) ? wv : wo;
  unsigned short* dst = Wb + (size_t)z * 1048576;
  const size_t i = ((size_t)blockIdx.x * 256 + threadIdx.x) * 8;
  float4 a = *(const float4*)(src + i);
  float4 b = *(const float4*)(src + i + 4);
  bhalf8 r;
  r[0] = (short)f2bf(a.x); r[1] = (short)f2bf(a.y);
  r[2] = (short)f2bf(a.z); r[3] = (short)f2bf(a.w);
  r[4] = (short)f2bf(b.x); r[5] = (short)f2bf(b.y);
  r[6] = (short)f2bf(b.z); r[7] = (short)f2bf(b.w);
  *(bhalf8*)(dst + i) = r;
}

// ---------------------------------------------------------------------------
// C[4096,1024] = A @ W^T + bias. 128x128 tile, BK=64, 4 waves (2x2 quadrants).
// XCD-chunked swizzle on the 256-block (x,y) grid for L2 locality.
// ---------------------------------------------------------------------------
template <bool BF16OUT>
__global__ __launch_bounds__(256) void mfma_gemm_kernel(
    const unsigned short* __restrict__ A0, const unsigned short* __restrict__ A1,
    const unsigned short* __restrict__ A2,
    const unsigned short* __restrict__ W0, const unsigned short* __restrict__ W1,
    const unsigned short* __restrict__ W2,
    const float* __restrict__ b0, const float* __restrict__ b1,
    const float* __restrict__ b2,
    void* __restrict__ C0, void* __restrict__ C1, void* __restrict__ C2) {
  const int z = blockIdx.z;
  const unsigned short* A = (z == 0) ? A0 : (z == 1) ? A1 : A2;
  const unsigned short* W = (z == 0) ? W0 : (z == 1) ? W1 : W2;
  const float* bias = (z == 0) ? b0 : (z == 1) ? b1 : b2;
  void* C = (z == 0) ? C0 : (z == 1) ? C1 : C2;
  const int lin = blockIdx.y * 8 + blockIdx.x;
  const int swz = (lin & 7) * 32 + (lin >> 3);
  const int m0 = (swz >> 3) * 128, n0 = (swz & 7) * 128;
  __shared__ unsigned short As[128 * 64];
  __shared__ unsigned short Ws[128 * 64];
  const int t = threadIdx.x, wave = t >> 6, lane = t & 63;
  const int wr = wave >> 1, wc = wave & 1;
  floatx4 acc[4][4];
  const floatx4 z4 = {0.f, 0.f, 0.f, 0.f};
#pragma unroll
  for (int i = 0; i < 4; ++i)
#pragma unroll
    for (int j = 0; j < 4; ++j) acc[i][j] = z4;

  for (int k0 = 0; k0 < 1024; k0 += 64) {
    stage_tile<16>(A + (size_t)m0 * 1024 + k0, As, wave, lane);
    stage_tile<16>(W + (size_t)n0 * 1024 + k0, Ws, wave, lane);
    __syncthreads();
#pragma unroll
    for (int ks = 0; ks < 2; ++ks) {
      const int kb = ks * 64 + ((lane >> 4) << 4);
      bhalf8 af[4], bf[4];
#pragma unroll
      for (int mi = 0; mi < 4; ++mi)
        af[mi] = read_frag(As, wr * 64 + mi * 16 + (lane & 15), kb);
#pragma unroll
      for (int ni = 0; ni < 4; ++ni)
        bf[ni] = read_frag(Ws, wc * 64 + ni * 16 + (lane & 15), kb);
#pragma unroll
      for (int mi = 0; mi < 4; ++mi)
#pragma unroll
        for (int ni = 0; ni < 4; ++ni)
          acc[mi][ni] = __builtin_amdgcn_mfma_f32_16x16x32_bf16(af[mi], bf[ni], acc[mi][ni], 0, 0, 0);
    }
    __syncthreads();
  }
#pragma unroll
  for (int mi = 0; mi < 4; ++mi)
#pragma unroll
    for (int ni = 0; ni < 4; ++ni) {
      const int col = n0 + wc * 64 + ni * 16 + (lane & 15);
      const float bv = bias[col];
#pragma unroll
      for (int r = 0; r < 4; ++r) {
        const int row = m0 + wr * 64 + mi * 16 + (lane >> 4) * 4 + r;
        const float v = acc[mi][ni][r] + bv;
        if (BF16OUT)
          ((unsigned short*)C)[(size_t)row * 1024 + col] = f2bf(v);
        else
          ((float*)C)[(size_t)row * 1024 + col] = v;
      }
    }
}

// ---------------------------------------------------------------------------
// In-place RoPE on bf16 [B,S,E]; one thread per channel pair.
// ---------------------------------------------------------------------------
__global__ __launch_bounds__(256) void rope_bf_kernel(unsigned int* __restrict__ X,
                                                      const int* __restrict__ idxs) {
  const int gid = blockIdx.x * 256 + threadIdx.x;
  const int i = gid & 511, bs = gid >> 9;
  const int pos = idxs[bs];
  const double freq = exp(-(double)(2 * i) * (9.210340371976184 / 1024.0));
  const double ang = fmod((double)pos * freq, 6.283185307179586476925287);
  const float fa = (float)ang;
  float sn, c;
  sincosf(fa, &sn, &c);
  const unsigned v = X[gid];
  const float x = bf2f((unsigned short)(v & 0xffffu));
  const float y = bf2f((unsigned short)(v >> 16));
  const float rx = x * c - y * sn;
  const float ry = x * sn + y * c;
  X[gid] = (unsigned)f2bf(rx) | ((unsigned)f2bf(ry) << 16);
}

// ---------------------------------------------------------------------------
// Vt[(b*16+h)*64 + d][s] = Vr[b][s][h*64+d]   (bf16 transpose, 64x64 tiles)
// ---------------------------------------------------------------------------
__global__ __launch_bounds__(256) void transpose_v_kernel(
    const unsigned short* __restrict__ Vr, unsigned short* __restrict__ Vt) {
  const int s0 = blockIdx.x * 64;
  const int bh = blockIdx.y;
  const int b = bh >> 4, h = bh & 15;
  __shared__ unsigned short L[64][72];
  const int t = threadIdx.x, r = t >> 2, cq = (t & 3) * 16;
  const unsigned short* src = Vr + ((size_t)(b * S_) + s0 + r) * E_ + h * HD_ + cq;
  *(bhalf8*)&L[r][cq] = *(const bhalf8*)src;
  *(bhalf8*)&L[r][cq + 8] = *(const bhalf8*)(src + 8);
  __syncthreads();
  bhalf8 o0, o1;
#pragma unroll
  for (int u = 0; u < 8; ++u) o0[u] = (short)L[cq + u][r];
#pragma unroll
  for (int u = 0; u < 8; ++u) o1[u] = (short)L[cq + 8 + u][r];
  unsigned short* dst = Vt + ((size_t)bh * 64 + r) * 1024 + s0 + cq;
  *(bhalf8*)dst = o0;
  *(bhalf8*)(dst + 8) = o1;
}

// ---------------------------------------------------------------------------
// scores + in-register softmax + bf16 P write. One head-batch per block.
// grid (64 qb, CH), 4 waves, 32KB LDS (5 blocks/CU). XCD-chunked swizzle.
//  QK^T swapped operands: lane (w,l4,l15) holds S[q=l15][k=w*256+mt*16+l4*4+r].
//  Mask from precomputed bitmask (32B/lane). Masking applied post-exp (zero).
//  Cross-wave reduce buffers aliased into Sbuf (written later).
// ---------------------------------------------------------------------------
__global__ __launch_bounds__(256) void scores_sm_kernel(
    const unsigned short* __restrict__ Qr, const unsigned short* __restrict__ Kr,
    unsigned short* __restrict__ P, const unsigned long long* __restrict__ Mbits,
    int hb0, int nwg) {
  // XCD swizzle: XCD x owns 8 consecutive head-batches (all their q-blocks).
  const int lin = blockIdx.y * 64 + blockIdx.x;
  const int q8 = nwg >> 3;
  const int swz = (lin & 7) * q8 + (lin >> 3);
  const int qb = swz & 63, lhb = swz >> 6;
  const int hb = hb0 + lhb;
  const int h = hb >> 2, b = hb & 3, bp = hb >> 4;
  const int q0 = qb * 16;
  __shared__ unsigned short Sbuf[16 * 1024];  // bf16 P, XOR-swizzled rows
  float* rptr = (float*)Sbuf;                 // [0,64): rmax, [64,128): rsum (aliased)
  const int t = threadIdx.x, w = t >> 6, lane = t & 63;
  const int l4 = lane >> 4, l15 = lane & 15;

  const char* Qb = (const char*)Qr + ((size_t)b << 21) + h * 128;
  const char* Kb = (const char*)Kr + ((size_t)b << 21) + h * 128;

  // Mask words for (q=q0+l15, k in [w*256, w*256+256))
  const unsigned long long* mrow =
      Mbits + ((size_t)bp << 14) + (size_t)(q0 + l15) * 16 + w * 4;
  unsigned long long mw0 = mrow[0], mw1 = mrow[1], mw2 = mrow[2], mw3 = mrow[3];

  // Q fragments (B-operand; rows q0+l15)
  bhalf8 bq0 = *(const bhalf8*)(Qb + (size_t)(q0 + l15) * 2048 + l4 * 16);
  bhalf8 bq1 = *(const bhalf8*)(Qb + (size_t)(q0 + l15) * 2048 + 64 + l4 * 16);

  // QK^T: wave w covers k in [w*256, w*256+256)
  floatx4 acc[16];
  const floatx4 z4 = {0.f, 0.f, 0.f, 0.f};
#pragma unroll
  for (int i = 0; i < 16; ++i) acc[i] = z4;
#pragma unroll
  for (int mt = 0; mt < 16; ++mt) {
    const char* kr = Kb + (size_t)(w * 256 + mt * 16 + l15) * 2048 + l4 * 16;
    bhalf8 a0 = *(const bhalf8*)kr;
    bhalf8 a1 = *(const bhalf8*)(kr + 64);
    acc[mt] = __builtin_amdgcn_mfma_f32_16x16x32_bf16(a0, bq0, acc[mt], 0, 0, 0);
    acc[mt] = __builtin_amdgcn_mfma_f32_16x16x32_bf16(a1, bq1, acc[mt], 0, 0, 0);
  }

  // Row max over ALL values (masked included; softmax invariant to over-max).
  float red[16];
#pragma unroll
  for (int mt = 0; mt < 16; ++mt)
    red[mt] = fmaxf(fmaxf(acc[mt][0], acc[mt][1]), fmaxf(acc[mt][2], acc[mt][3]));
#pragma unroll
  for (int s2 = 8; s2 > 0; s2 >>= 1)
#pragma unroll
    for (int i = 0; i < 8; ++i)
      if (i < s2) red[i] = fmaxf(red[i], red[i + s2]);
  float mx = red[0];
  mx = fmaxf(mx, __shfl_xor(mx, 16));
  mx = fmaxf(mx, __shfl_xor(mx, 32));
  if (l4 == 0) rptr[w * 16 + l15] = mx;
  __syncthreads();
  mx = fmaxf(fmaxf(rptr[l15], rptr[16 + l15]), fmaxf(rptr[32 + l15], rptr[48 + l15]));

  // exp2 with folded 1/8 scale; then zero masked entries.
  const float Cc = 0.18033688011112042f;  // 0.125 * log2(e)
  const float mc = mx * Cc;
#pragma unroll
  for (int mt = 0; mt < 16; ++mt) {
    const unsigned long long mwv = (mt < 4) ? mw0 : (mt < 8) ? mw1 : (mt < 12) ? mw2 : mw3;
    const unsigned bits = (unsigned)(mwv >> ((mt & 3) * 16 + l4 * 4)) & 0xFu;
#pragma unroll
    for (int r = 0; r < 4; ++r) {
      float e = exp2f(__builtin_fmaf(acc[mt][r], Cc, -mc));
      acc[mt][r] = ((bits >> r) & 1u) ? 0.f : e;
    }
  }

  // Row sum.
#pragma unroll
  for (int mt = 0; mt < 16; ++mt)
    red[mt] = (acc[mt][0] + acc[mt][1]) + (acc[mt][2] + acc[mt][3]);
#pragma unroll
  for (int s2 = 8; s2 > 0; s2 >>= 1)
#pragma unroll
    for (int i = 0; i < 8; ++i)
      if (i < s2) red[i] += red[i + s2];
  float sm = red[0];
  sm += __shfl_xor(sm, 16);
  sm += __shfl_xor(sm, 32);
  if (l4 == 0) rptr[64 + w * 16 + l15] = sm;
  __syncthreads();
  sm = (rptr[64 + l15] + rptr[80 + l15]) + (rptr[96 + l15] + rptr[112 + l15]);
  const float inv = 1.0f / sm;
  __syncthreads();  // protect aliased reduce region before Sbuf overwrite

  // Normalize, pack to bf16, write into swizzled Sbuf.
  const int xr = (l15 & 7) << 4;
#pragma unroll
  for (int mt = 0; mt < 16; ++mt) {
    uint2 pk;
    pk.x = cvtpk_bf16(acc[mt][0] * inv, acc[mt][1] * inv);
    pk.y = cvtpk_bf16(acc[mt][2] * inv, acc[mt][3] * inv);
    const int kb2 = (w * 256 + mt * 16 + l4 * 4) * 2;
    *(uint2*)((char*)Sbuf + l15 * 2048 + (kb2 ^ xr)) = pk;
  }
  __syncthreads();

  // Coalesced P write: wave w handles rows w*4..w*4+3.
  unsigned short* pbase = P + ((size_t)lhb << 20);
#pragma unroll
  for (int rr = 0; rr < 4; ++rr) {
    const int ql = w * 4 + rr;
    const int gq = q0 + ql;
    const int xq = (ql & 7) << 4;
#pragma unroll
    for (int j = 0; j < 2; ++j) {
      bhalf8 v = *(const bhalf8*)((const char*)Sbuf + ql * 2048 +
                                  ((j * 1024 + lane * 16) ^ xq));
      *(bhalf8*)(pbase + ((size_t)gq << 10) + j * 512 + lane * 8) = v;
    }
  }
}

// ---------------------------------------------------------------------------
// outW[b][q][k] += (1/16) * sum_hh P[hh*4+b][q][k]   (this chunk's heads)
// ---------------------------------------------------------------------------
__global__ __launch_bounds__(256) void wmean_kernel(
    const unsigned short* __restrict__ P, float* __restrict__ outW,
    int nhh, int first) {
  const size_t gid = (size_t)blockIdx.x * 256 + threadIdx.x;  // one per 8 k
  const int k8 = (int)(gid & 127);
  const int q = (int)((gid >> 7) & 1023);
  const int b = (int)(gid >> 17);
  float s[8];
#pragma unroll
  for (int u = 0; u < 8; ++u) s[u] = 0.f;
  for (int hh = 0; hh < nhh; ++hh) {
    const int lhb = hh * 4 + b;
    bhalf8 v = *(const bhalf8*)(P + ((size_t)lhb << 20) + ((size_t)q << 10) + k8 * 8);
#pragma unroll
    for (int u = 0; u < 8; ++u) s[u] += bf2f((unsigned short)v[u]);
  }
  float* o = outW + (((size_t)(b * S_ + q)) << 10) + k8 * 8;
  const float invH = 1.0f / 16.0f;
  float4 v0, v1;
  v0.x = s[0] * invH; v0.y = s[1] * invH; v0.z = s[2] * invH; v0.w = s[3] * invH;
  v1.x = s[4] * invH; v1.y = s[5] * invH; v1.z = s[6] * invH; v1.w = s[7] * invH;
  if (!first) {
    float4 a = *(float4*)o, b4 = *(float4*)(o + 4);
    v0.x += a.x; v0.y += a.y; v0.z += a.z; v0.w += a.w;
    v1.x += b4.x; v1.y += b4.y; v1.z += b4.z; v1.w += b4.w;
  }
  *(float4*)o = v0;
  *(float4*)(o + 4) = v1;
}

// ---------------------------------------------------------------------------
// PV: Ocat[b][q][h*64+d] = sum_k P[lhb][q][k] * Vt[bh*64+d][k]
// 64q x 64d per block, BK=64, 4 waves in 2x2. grid (16 qtiles, CH), XCD swz.
// ---------------------------------------------------------------------------
__global__ __launch_bounds__(256) void pv_mfma_kernel(
    const unsigned short* __restrict__ Wt, const unsigned short* __restrict__ Vt,
    unsigned short* __restrict__ Ocat, int hb0, int nwg) {
  const int lin = blockIdx.y * 16 + blockIdx.x;
  const int q8 = nwg >> 3;
  const int swz = (lin & 7) * q8 + (lin >> 3);
  const int qt = swz & 15, lhb = swz >> 4;
  const int hb = hb0 + lhb;
  const int h = hb >> 2, b = hb & 3;
  const int q0 = qt * 64;
  __shared__ unsigned short Ps[64 * 64];
  __shared__ unsigned short Vs[64 * 64];
  const int t = threadIdx.x, wave = t >> 6, lane = t & 63;
  const int wr = wave >> 1, wc = wave & 1;
  const unsigned short* Wh = Wt + ((size_t)lhb << 20);
  const unsigned short* Vh = Vt + (size_t)(b * 16 + h) * 65536;
  floatx4 acc[2][2];
  const floatx4 z4 = {0.f, 0.f, 0.f, 0.f};
#pragma unroll
  for (int i = 0; i < 2; ++i)
#pragma unroll
    for (int j = 0; j < 2; ++j) acc[i][j] = z4;

  for (int k0 = 0; k0 < 1024; k0 += 64) {
    stage_tile<8>(Wh + (size_t)q0 * 1024 + k0, Ps, wave, lane);
    stage_tile<8>(Vh + k0, Vs, wave, lane);
    __syncthreads();
#pragma unroll
    for (int ks = 0; ks < 2; ++ks) {
      const int kb = ks * 64 + ((lane >> 4) << 4);
      bhalf8 af[2], bf[2];
#pragma unroll
      for (int mi = 0; mi < 2; ++mi)
        af[mi] = read_frag(Ps, wr * 32 + mi * 16 + (lane & 15), kb);
#pragma unroll
      for (int ni = 0; ni < 2; ++ni)
        bf[ni] = read_frag(Vs, wc * 32 + ni * 16 + (lane & 15), kb);
#pragma unroll
      for (int mi = 0; mi < 2; ++mi)
#pragma unroll
        for (int ni = 0; ni < 2; ++ni)
          acc[mi][ni] = __builtin_amdgcn_mfma_f32_16x16x32_bf16(af[mi], bf[ni], acc[mi][ni], 0, 0, 0);
    }
    __syncthreads();
  }
#pragma unroll
  for (int mi = 0; mi < 2; ++mi)
#pragma unroll
    for (int ni = 0; ni < 2; ++ni) {
      const int d = wc * 32 + ni * 16 + (lane & 15);
#pragma unroll
      for (int r = 0; r < 4; ++r) {
        const int q = q0 + wr * 32 + mi * 16 + (lane >> 4) * 4 + r;
        Ocat[((size_t)(b * S_) + q) * E_ + h * HD_ + d] = f2bf(acc[mi][ni][r]);
      }
    }
}

// ---------------------------------------------------------------------------
extern "C" void kernel_launch(void* const* d_in, const int* in_sizes, int n_in,
                              void* d_out, int out_size, void* d_ws, size_t ws_size,
                              hipStream_t stream) {
  (void)in_sizes; (void)n_in; (void)out_size;
  const float* query = (const float*)d_in[0];
  const float* key   = (const float*)d_in[1];
  const float* value = (const float*)d_in[2];
  const int* qidx = (const int*)d_in[3];
  const int* kidx = (const int*)d_in[4];
  const void* amask = d_in[5];
  const void* kpm   = d_in[6];
  const float* Wq = (const float*)d_in[7];
  const float* bq = (const float*)d_in[8];
  const float* Wk = (const float*)d_in[9];
  const float* bk = (const float*)d_in[10];
  const float* Wv = (const float*)d_in[11];
  const float* bv = (const float*)d_in[12];
  const float* Wo = (const float*)d_in[13];
  const float* bo = (const float*)d_in[14];

  float* outA = (float*)d_out;                          // [B,S,E] fp32
  float* outW = (float*)d_out + (size_t)B_ * S_ * E_;   // [B,S,S] fp32

  float* ws = (float*)d_ws;
  unsigned short* Ab   = (unsigned short*)(ws + 0);         // 3x 4,194,304 bf16
  unsigned short* Wb   = (unsigned short*)(ws + 6291456);   // 4x 1,048,576 bf16
  unsigned short* Qr   = (unsigned short*)(ws + 8388608);
  unsigned short* Kr   = (unsigned short*)(ws + 10485760);
  unsigned short* Vr   = (unsigned short*)(ws + 12582912);
  unsigned short* Vt   = (unsigned short*)(ws + 14680064);
  unsigned short* Ocat = (unsigned short*)(ws + 16777216);
  int* flagp           = (int*)(ws + 18874368);
  unsigned long long* Mbits = (unsigned long long*)(ws + 18874432);  // 512 KB
  const size_t tail_off = 18874432 + 131072;  // floats

  // P chunk: per head-batch 1024*1024 bf16 = 524288 floats.
  const size_t ws_floats = ws_size / 4;
  int CH = 0;
  unsigned short* P = nullptr;
  for (int c = 64; c >= 8; c >>= 1) {
    if (tail_off + (size_t)c * 524288 <= ws_floats) {
      CH = c;
      P = (unsigned short*)(ws + tail_off);
      break;
    }
  }
  if (!CH) {  // alias the Ab region (dead after the QKV GEMM): 6.29M floats >= 8 planes
    CH = 8;
    P = (unsigned short*)ws;
  }

  detect_bool_kernel<<<1, 64, 0, stream>>>((const uint8_t*)amask, flagp);
  mprep_kernel<<<256, 256, 0, stream>>>(amask, kpm, flagp, Mbits);

  cvt_in_kernel<<<dim3(2048, 1, 3), 256, 0, stream>>>(query, key, value, Ab);
  cvt_w_kernel<<<dim3(512, 1, 4), 256, 0, stream>>>(Wq, Wk, Wv, Wo, Wb);

  mfma_gemm_kernel<true><<<dim3(8, 32, 3), 256, 0, stream>>>(
      Ab, Ab + 4194304, Ab + 8388608,
      Wb, Wb + 1048576, Wb + 2097152,
      bq, bk, bv, Qr, Kr, Vr);

  rope_bf_kernel<<<8192, 256, 0, stream>>>((unsigned int*)Qr, qidx);
  rope_bf_kernel<<<8192, 256, 0, stream>>>((unsigned int*)Kr, kidx);

  transpose_v_kernel<<<dim3(16, 64), 256, 0, stream>>>(Vr, Vt);

  const int nch = HB_ / CH;
  for (int c = 0; c < nch; ++c) {
    const int hb0 = c * CH;
    scores_sm_kernel<<<dim3(64, CH), 256, 0, stream>>>(Qr, Kr, P, Mbits, hb0,
                                                       64 * CH);
    wmean_kernel<<<2048, 256, 0, stream>>>(P, outW, CH / 4, (c == 0) ? 1 : 0);
    pv_mfma_kernel<<<dim3(16, CH), 256, 0, stream>>>(P, Vt, Ocat, hb0, 16 * CH);
  }

  mfma_gemm_kernel<false><<<dim3(8, 32, 1), 256, 0, stream>>>(
      Ocat, Ocat, Ocat, Wb + 3145728, Wb + 3145728, Wb + 3145728,
      bo, bo, bo, outA, outA, outA);
}